// Round 1
// baseline (699.994 us; speedup 1.0000x reference)
//
#include <hip/hip_runtime.h>
#include <stdint.h>

#define T_SEQ 2048
#define HIDDEN 4096
#define NHEAD 32
#define NKV 8
#define HDIM 128
#define QKVN 6144  // (32 + 2*8) * 128

typedef __bf16 bf16x8 __attribute__((ext_vector_type(8)));
typedef float f32x4 __attribute__((ext_vector_type(4)));
typedef unsigned short u16;
typedef u16 u16x8 __attribute__((ext_vector_type(8)));
typedef u16 u16x4 __attribute__((ext_vector_type(4)));

__device__ __forceinline__ u16 f2bf(float f) {
  uint32_t u = __builtin_bit_cast(uint32_t, f);
  u = (u + 0x7fffu + ((u >> 16) & 1u)) >> 16;
  return (u16)u;
}
__device__ __forceinline__ float bf2f(u16 h) {
  uint32_t u = ((uint32_t)h) << 16;
  return __builtin_bit_cast(float, u);
}

// async global->LDS, 16B per lane. LDS dest is wave-uniform base + lane*16.
__device__ __forceinline__ void gload16(const void* g, void* l) {
  __builtin_amdgcn_global_load_lds(
      (__attribute__((address_space(1))) void*)(uintptr_t)g,
      (__attribute__((address_space(3))) void*)(uintptr_t)l, 16, 0, 0);
}

// ---------------- fp32 -> bf16 convert ----------------
__global__ void cvt_f32_bf16(const float* __restrict__ in, u16* __restrict__ out, int n) {
  int i = (blockIdx.x * blockDim.x + threadIdx.x) * 4;
  int stride = gridDim.x * blockDim.x * 4;
  for (; i < n; i += stride) {
    float4 v = *(const float4*)(in + i);
    u16x4 o;
    o.x = f2bf(v.x); o.y = f2bf(v.y); o.z = f2bf(v.z); o.w = f2bf(v.w);
    *(u16x4*)(out + i) = o;
  }
}

// ---------------- RoPE (neox), in-place on bf16 qkv ----------------
__global__ void rope_kernel(u16* __restrict__ qkv, const int* __restrict__ pos) {
  int idx = blockIdx.x * blockDim.x + threadIdx.x;
  if (idx >= T_SEQ * 40 * 64) return;
  int i = idx & 63;
  int head = (idx >> 6) % 40;
  int t = idx / (40 * 64);
  int base = head < NHEAD ? head * HDIM : NHEAD * HDIM + (head - NHEAD) * HDIM;
  float p = (float)pos[t];
  // inv_freq = 10000^(-i/64) = 2^(-i * log2(10000)/64)
  float inv_freq = exp2f(-(float)i * (13.287712379549449f / 64.0f));
  float ang = p * inv_freq;
  float s, c;
  sincosf(ang, &s, &c);
  u16* p1 = qkv + (size_t)t * QKVN + base + i;
  u16* p2 = p1 + 64;
  float x1 = bf2f(*p1), x2 = bf2f(*p2);
  *p1 = f2bf(x1 * c - x2 * s);
  *p2 = f2bf(x2 * c + x1 * s);
}

// ---------------- NT GEMM: C[M][N] = A[M][K] * B[N][K]^T (bf16 in, fp32 acc) ----
__device__ __forceinline__ void storeC(float* p, float v) { *p = v; }
__device__ __forceinline__ void storeC(u16* p, float v) { *p = f2bf(v); }

template <typename OutT>
__global__ void __launch_bounds__(256)
gemm_nt(const u16* __restrict__ A, const u16* __restrict__ B,
        OutT* __restrict__ C, int M, int N, int K) {
  __shared__ u16 As[128 * 32];
  __shared__ u16 Bs[128 * 32];
  const int tid = threadIdx.x;
  const int lane = tid & 63;
  const int w = tid >> 6;
  const int wr = (w >> 1) * 64;
  const int wc = (w & 1) * 64;
  const int l15 = lane & 15, lg = lane >> 4;
  const int bn = blockIdx.x * 128;
  const int bm = blockIdx.y * 128;

  // staging: wave w covers rows [w*32, w*32+32) of each 128x32 tile, 2 rounds
  const int srow = lane >> 2;          // 0..15
  const int skoff = (lane & 3) * 8;    // 0,8,16,24
  const u16* Ap0 = A + (size_t)(bm + w * 32 + srow) * K + skoff;
  const u16* Ap1 = Ap0 + (size_t)16 * K;
  const u16* Bp0 = B + (size_t)(bn + w * 32 + srow) * K + skoff;
  const u16* Bp1 = Bp0 + (size_t)16 * K;
  u16* Asb0 = &As[w * 1024];
  u16* Asb1 = &As[w * 1024 + 512];
  u16* Bsb0 = &Bs[w * 1024];
  u16* Bsb1 = &Bs[w * 1024 + 512];

  f32x4 acc[4][4] = {};

  for (int kt = 0; kt < K; kt += 32) {
    gload16(Ap0, Asb0);
    gload16(Ap1, Asb1);
    gload16(Bp0, Bsb0);
    gload16(Bp1, Bsb1);
    Ap0 += 32; Ap1 += 32; Bp0 += 32; Bp1 += 32;
    __syncthreads();  // drains vmcnt before barrier (compiler-inserted)
    bf16x8 af[4], bfv[4];
#pragma unroll
    for (int mi = 0; mi < 4; ++mi)
      af[mi] = *(const bf16x8*)&As[(wr + mi * 16 + l15) * 32 + lg * 8];
#pragma unroll
    for (int ni = 0; ni < 4; ++ni)
      bfv[ni] = *(const bf16x8*)&Bs[(wc + ni * 16 + l15) * 32 + lg * 8];
#pragma unroll
    for (int mi = 0; mi < 4; ++mi)
#pragma unroll
      for (int ni = 0; ni < 4; ++ni)
        acc[mi][ni] = __builtin_amdgcn_mfma_f32_16x16x32_bf16(af[mi], bfv[ni], acc[mi][ni], 0, 0, 0);
    __syncthreads();
  }

#pragma unroll
  for (int mi = 0; mi < 4; ++mi)
#pragma unroll
    for (int ni = 0; ni < 4; ++ni)
#pragma unroll
      for (int r = 0; r < 4; ++r) {
        int row = bm + wr + mi * 16 + lg * 4 + r;
        int col = bn + wc + ni * 16 + l15;
        storeC(&C[(size_t)row * N + col], acc[mi][ni][r]);
      }
}

// ---------------- causal GQA flash attention ----------------
// grid: (T/64, NHEAD), block 256 (4 waves x 16 q-rows). bf16 in/out, fp32 state.
__global__ void __launch_bounds__(256)
attn_kernel(const u16* __restrict__ qkv, u16* __restrict__ out) {
  __shared__ u16 Vt[128 * 80];       // V^T [d][kv], row stride 80 (160B, 16B-aligned)
  __shared__ u16 Pl[4][16 * 80];     // per-wave P [row][kv], stride 80

  const int tid = threadIdx.x;
  const int lane = tid & 63;
  const int w = tid >> 6;
  const int l15 = lane & 15, lg = lane >> 4;
  const int h = blockIdx.y;
  const int kvh = h >> 2;            // GQA: 4 q-heads per kv-head
  const int q0 = (gridDim.x - 1 - blockIdx.x) * 64;  // heavy tiles dispatch first

  // Q fragments in registers (post-RoPE)
  bf16x8 qa[4];
  {
    const u16* qrow = qkv + (size_t)(q0 + w * 16 + l15) * QKVN + h * HDIM + lg * 8;
#pragma unroll
    for (int ks = 0; ks < 4; ++ks) qa[ks] = *(const bf16x8*)(qrow + ks * 32);
  }

  f32x4 acc_o[8] = {};
  float m[4], lsum[4];
#pragma unroll
  for (int r = 0; r < 4; ++r) { m[r] = -1e30f; lsum[r] = 0.f; }

  const float scale = 0.088388347648318447f;  // 1/sqrt(128)

  for (int kv0 = 0; kv0 <= q0; kv0 += 64) {
    __syncthreads();  // protect Vt from previous iteration's readers
    // stage V^T: 64 kv rows x 128 d
    {
      int kvr = tid >> 4;            // 0..15
      int d0 = (tid & 15) * 8;
#pragma unroll
      for (int rnd = 0; rnd < 4; ++rnd) {
        int kv = rnd * 16 + kvr;
        u16x8 v = *(const u16x8*)(qkv + (size_t)(kv0 + kv) * QKVN + (NHEAD + NKV) * HDIM + kvh * HDIM + d0);
#pragma unroll
        for (int j = 0; j < 8; ++j) Vt[(d0 + j) * 80 + kv] = v[j];
      }
    }
    __syncthreads();

    // S = Q K^T  (16 rows x 64 kv per wave)
    f32x4 s[4] = {};
#pragma unroll
    for (int ks = 0; ks < 4; ++ks) {
#pragma unroll
      for (int n = 0; n < 4; ++n) {
        bf16x8 kf = *(const bf16x8*)(qkv + (size_t)(kv0 + n * 16 + l15) * QKVN + NHEAD * HDIM + kvh * HDIM + ks * 32 + lg * 8);
        s[n] = __builtin_amdgcn_mfma_f32_16x16x32_bf16(qa[ks], kf, s[n], 0, 0, 0);
      }
    }

    // online softmax
    const bool diag = (kv0 == q0);
    float alpha[4];
#pragma unroll
    for (int r = 0; r < 4; ++r) {
      int tq = q0 + w * 16 + lg * 4 + r;
      float mx = -1e30f;
#pragma unroll
      for (int n = 0; n < 4; ++n) {
        float v = s[n][r] * scale;
        if (diag && (kv0 + n * 16 + l15) > tq) v = -1e30f;
        s[n][r] = v;
        mx = fmaxf(mx, v);
      }
#pragma unroll
      for (int msk = 1; msk < 16; msk <<= 1) mx = fmaxf(mx, __shfl_xor(mx, msk, 64));
      float mn = fmaxf(m[r], mx);
      alpha[r] = __expf(m[r] - mn);
      m[r] = mn;
      float ps = 0.f;
#pragma unroll
      for (int n = 0; n < 4; ++n) {
        float p = __expf(s[n][r] - mn);
        s[n][r] = p;
        ps += p;
      }
#pragma unroll
      for (int msk = 1; msk < 16; msk <<= 1) ps += __shfl_xor(ps, msk, 64);
      lsum[r] = lsum[r] * alpha[r] + ps;
#pragma unroll
      for (int n = 0; n < 4; ++n)
        Pl[w][(lg * 4 + r) * 80 + n * 16 + l15] = f2bf(s[n][r]);
    }
#pragma unroll
    for (int f = 0; f < 8; ++f)
#pragma unroll
      for (int r = 0; r < 4; ++r) acc_o[f][r] *= alpha[r];

    // O += P V
#pragma unroll
    for (int ks = 0; ks < 2; ++ks) {
      bf16x8 pa = *(const bf16x8*)&Pl[w][l15 * 80 + ks * 32 + lg * 8];
#pragma unroll
      for (int nd = 0; nd < 8; ++nd) {
        bf16x8 bv = *(const bf16x8*)&Vt[(nd * 16 + l15) * 80 + ks * 32 + lg * 8];
        acc_o[nd] = __builtin_amdgcn_mfma_f32_16x16x32_bf16(pa, bv, acc_o[nd], 0, 0, 0);
      }
    }
  }

  // epilogue: out[t][h*128+d] = O / lsum
#pragma unroll
  for (int nd = 0; nd < 8; ++nd)
#pragma unroll
    for (int r = 0; r < 4; ++r) {
      int row = q0 + w * 16 + lg * 4 + r;
      int col = h * HDIM + nd * 16 + l15;
      out[(size_t)row * (NHEAD * HDIM) + col] = f2bf(acc_o[nd][r] / lsum[r]);
    }
}

// ---------------- launcher ----------------
extern "C" void kernel_launch(void* const* d_in, const int* in_sizes, int n_in,
                              void* d_out, int out_size, void* d_ws, size_t ws_size,
                              hipStream_t stream) {
  const float* hs   = (const float*)d_in[0];
  const int*   pos  = (const int*)d_in[1];
  const float* wqkv = (const float*)d_in[2];
  const float* wo   = (const float*)d_in[3];
  float* out = (float*)d_out;
  uint8_t* ws = (uint8_t*)d_ws;

  // workspace layout (bytes)
  // hs_bf:   16,777,216  @ 0
  // wqkv_bf: 50,331,648  @ 16,777,216
  // wo_bf:   33,554,432  @ 67,108,864
  // qkv_bf:  25,165,824  @ 100,663,296
  // attn_bf: 16,777,216  @ 125,829,120   (total 142,606,336)
  if (ws_size < 142606336u) return;
  u16* hs_bf   = (u16*)(ws + 0);
  u16* wqkv_bf = (u16*)(ws + 16777216u);
  u16* wo_bf   = (u16*)(ws + 67108864u);
  u16* qkv_bf  = (u16*)(ws + 100663296u);
  u16* attn_bf = (u16*)(ws + 125829120u);

  cvt_f32_bf16<<<2048, 256, 0, stream>>>(hs, hs_bf, T_SEQ * HIDDEN);
  cvt_f32_bf16<<<2048, 256, 0, stream>>>(wqkv, wqkv_bf, QKVN * HIDDEN);
  cvt_f32_bf16<<<2048, 256, 0, stream>>>(wo, wo_bf, HIDDEN * HIDDEN);

  gemm_nt<u16><<<dim3(QKVN / 128, T_SEQ / 128), 256, 0, stream>>>(
      hs_bf, wqkv_bf, qkv_bf, T_SEQ, QKVN, HIDDEN);

  rope_kernel<<<(T_SEQ * 40 * 64) / 256, 256, 0, stream>>>(qkv_bf, pos);

  attn_kernel<<<dim3(T_SEQ / 64, NHEAD), 256, 0, stream>>>(qkv_bf, attn_bf);

  gemm_nt<float><<<dim3(HIDDEN / 128, T_SEQ / 128), 256, 0, stream>>>(
      attn_bf, wo_bf, out, T_SEQ, HIDDEN, HIDDEN);
}

// Round 2
// 408.813 us; speedup vs baseline: 1.7123x; 1.7123x over previous
//
#include <hip/hip_runtime.h>
#include <stdint.h>

#define T_SEQ 2048
#define HIDDEN 4096
#define NHEAD 32
#define NKV 8
#define HDIM 128
#define QKVN 6144  // (32 + 2*8) * 128

typedef __bf16 bf16x8 __attribute__((ext_vector_type(8)));
typedef float f32x4 __attribute__((ext_vector_type(4)));
typedef unsigned short u16;
typedef u16 u16x8 __attribute__((ext_vector_type(8)));
typedef u16 u16x4 __attribute__((ext_vector_type(4)));

__device__ __forceinline__ u16 f2bf(float f) {
  uint32_t u = __builtin_bit_cast(uint32_t, f);
  u = (u + 0x7fffu + ((u >> 16) & 1u)) >> 16;
  return (u16)u;
}
__device__ __forceinline__ float bf2f(u16 h) {
  uint32_t u = ((uint32_t)h) << 16;
  return __builtin_bit_cast(float, u);
}

// async global->LDS, 16B per lane. LDS dest must be wave-uniform; HW adds lane*16.
__device__ __forceinline__ void gload16(const void* g, void* l) {
  __builtin_amdgcn_global_load_lds(
      (__attribute__((address_space(1))) void*)(uintptr_t)g,
      (__attribute__((address_space(3))) void*)(uintptr_t)l, 16, 0, 0);
}

// ---------------- fp32 -> bf16 convert ----------------
__global__ void cvt_f32_bf16(const float* __restrict__ in, u16* __restrict__ out, int n) {
  int i = (blockIdx.x * blockDim.x + threadIdx.x) * 4;
  int stride = gridDim.x * blockDim.x * 4;
  for (; i < n; i += stride) {
    float4 v = *(const float4*)(in + i);
    u16x4 o;
    o.x = f2bf(v.x); o.y = f2bf(v.y); o.z = f2bf(v.z); o.w = f2bf(v.w);
    *(u16x4*)(out + i) = o;
  }
}

// ---------------- RoPE (neox), in-place on bf16 qkv ----------------
__global__ void rope_kernel(u16* __restrict__ qkv, const int* __restrict__ pos) {
  int idx = blockIdx.x * blockDim.x + threadIdx.x;
  if (idx >= T_SEQ * 40 * 64) return;
  int i = idx & 63;
  int head = (idx >> 6) % 40;
  int t = idx / (40 * 64);
  int base = head < NHEAD ? head * HDIM : NHEAD * HDIM + (head - NHEAD) * HDIM;
  float p = (float)pos[t];
  float inv_freq = exp2f(-(float)i * (13.287712379549449f / 64.0f));
  float ang = p * inv_freq;
  float s, c;
  sincosf(ang, &s, &c);
  u16* p1 = qkv + (size_t)t * QKVN + base + i;
  u16* p2 = p1 + 64;
  float x1 = bf2f(*p1), x2 = bf2f(*p2);
  *p1 = f2bf(x1 * c - x2 * s);
  *p2 = f2bf(x2 * c + x1 * s);
}

// ---------------- NT GEMM: C[M][N] = A[M][K] * B[N][K]^T (bf16 in, fp32 acc) ----
__device__ __forceinline__ void storeC(float* p, float v) { *p = v; }
__device__ __forceinline__ void storeC(u16* p, float v) { *p = f2bf(v); }

template <typename OutT>
__global__ void __launch_bounds__(256)
gemm_nt(const u16* __restrict__ A, const u16* __restrict__ B,
        OutT* __restrict__ C, int M, int N, int K) {
  __shared__ u16 As[128 * 32];
  __shared__ u16 Bs[128 * 32];
  const int tid = threadIdx.x;
  const int lane = tid & 63;
  const int w = tid >> 6;
  const int wr = (w >> 1) * 64;
  const int wc = (w & 1) * 64;
  const int l15 = lane & 15, lg = lane >> 4;
  const int bn = blockIdx.x * 128;
  const int bm = blockIdx.y * 128;

  const int srow = lane >> 2;
  const int skoff = (lane & 3) * 8;
  const u16* Ap0 = A + (size_t)(bm + w * 32 + srow) * K + skoff;
  const u16* Ap1 = Ap0 + (size_t)16 * K;
  const u16* Bp0 = B + (size_t)(bn + w * 32 + srow) * K + skoff;
  const u16* Bp1 = Bp0 + (size_t)16 * K;
  u16* Asb0 = &As[w * 1024];
  u16* Asb1 = &As[w * 1024 + 512];
  u16* Bsb0 = &Bs[w * 1024];
  u16* Bsb1 = &Bs[w * 1024 + 512];

  f32x4 acc[4][4] = {};

  for (int kt = 0; kt < K; kt += 32) {
    gload16(Ap0, Asb0);
    gload16(Ap1, Asb1);
    gload16(Bp0, Bsb0);
    gload16(Bp1, Bsb1);
    Ap0 += 32; Ap1 += 32; Bp0 += 32; Bp1 += 32;
    __syncthreads();
    bf16x8 af[4], bfv[4];
#pragma unroll
    for (int mi = 0; mi < 4; ++mi)
      af[mi] = *(const bf16x8*)&As[(wr + mi * 16 + l15) * 32 + lg * 8];
#pragma unroll
    for (int ni = 0; ni < 4; ++ni)
      bfv[ni] = *(const bf16x8*)&Bs[(wc + ni * 16 + l15) * 32 + lg * 8];
#pragma unroll
    for (int mi = 0; mi < 4; ++mi)
#pragma unroll
      for (int ni = 0; ni < 4; ++ni)
        acc[mi][ni] = __builtin_amdgcn_mfma_f32_16x16x32_bf16(af[mi], bfv[ni], acc[mi][ni], 0, 0, 0);
    __syncthreads();
  }

#pragma unroll
  for (int mi = 0; mi < 4; ++mi)
#pragma unroll
    for (int ni = 0; ni < 4; ++ni)
#pragma unroll
      for (int r = 0; r < 4; ++r) {
        int row = bm + wr + mi * 16 + lg * 4 + r;
        int col = bn + wc + ni * 16 + l15;
        storeC(&C[(size_t)row * N + col], acc[mi][ni][r]);
      }
}

// ---------------- causal GQA flash attention ----------------
// grid: 1024 blocks (bid&7 = kv-head for XCD L2 locality; heavy q-tiles first).
// block: 256 thr, 4 waves x 16 q-rows, one q-head, 64-row q-tile, 64-kv tiles.
// K double-buffered in LDS via global_load_lds with pre-swizzled source (T2+#21);
// V double-buffered, reg-staged transpose with double-XOR swizzle; one barrier/tile.
__global__ void __launch_bounds__(256)
attn_kernel(const u16* __restrict__ qkv, u16* __restrict__ out) {
  __shared__ u16 Ksh[2][64 * 128];   // [kv][d], 16B slot s holds d-slot s^(kv&7)
  __shared__ u16 Vsh[2][128 * 64];   // V^T [d][kv], slot s holds kv-slot s^(d&7)^((d>>3)&7)
  __shared__ u16 Psh[4][16 * 64];    // per-wave P [row][kv], slot s holds kv-slot s^(row&7)

  const int tid = threadIdx.x;
  const int lane = tid & 63;
  const int w = tid >> 6;
  const int l15 = lane & 15, lg = lane >> 4;

  const int bid = blockIdx.x;
  const int kvh = bid & 7;             // XCD-pinned kv-head
  const int hg = (bid >> 3) & 3;
  const int qi = 31 - (bid >> 5);      // heavy tiles dispatch first
  const int h = kvh * 4 + hg;
  const int q0 = qi * 64;
  const int nt = qi + 1;

  const u16* Kg = qkv + NHEAD * HDIM + kvh * HDIM;
  const u16* Vg = qkv + (NHEAD + NKV) * HDIM + kvh * HDIM;

  // Q fragments in registers (post-RoPE)
  bf16x8 qa[4];
  {
    const u16* qrow = qkv + (size_t)(q0 + w * 16 + l15) * QKVN + h * HDIM + lg * 8;
#pragma unroll
    for (int ks = 0; ks < 4; ++ks) qa[ks] = *(const bf16x8*)(qrow + ks * 32);
  }

  f32x4 acc_o[8] = {};
  float m[4], lsum[4];
#pragma unroll
  for (int r = 0; r < 4; ++r) { m[r] = -1e30f; lsum[r] = 0.f; }

  const float scale = 0.088388347648318447f;  // 1/sqrt(128)

#define STAGE_K(kv0, p)                                                        \
  {                                                                            \
    _Pragma("unroll") for (int rnd = 0; rnd < 4; ++rnd) {                      \
      int cc = rnd * 256 + tid;                                                \
      int krow = cc >> 4, kslot = cc & 15;                                     \
      gload16(Kg + (size_t)((kv0) + krow) * QKVN + (kslot ^ (krow & 7)) * 8,   \
              &Ksh[p][(rnd * 256 + w * 64) * 8]);                              \
    }                                                                          \
  }
#define LOAD_V(kv0, vr)                                                        \
  {                                                                            \
    _Pragma("unroll") for (int rnd = 0; rnd < 4; ++rnd) {                      \
      int cc = rnd * 256 + tid;                                                \
      int vrow = cc >> 4, d0 = (cc & 15) * 8;                                  \
      vr[rnd] = *(const u16x8*)(Vg + (size_t)((kv0) + vrow) * QKVN + d0);      \
    }                                                                          \
  }
#define WRITE_V(vr, p)                                                         \
  {                                                                            \
    _Pragma("unroll") for (int rnd = 0; rnd < 4; ++rnd) {                      \
      int cc = rnd * 256 + tid;                                                \
      int vrow = cc >> 4, d0 = (cc & 15) * 8;                                  \
      _Pragma("unroll") for (int j = 0; j < 8; ++j) {                          \
        int d = d0 + j;                                                        \
        Vsh[p][d * 64 + (((vrow >> 3) ^ (d & 7) ^ ((d >> 3) & 7)) * 8) +       \
               (vrow & 7)] = vr[rnd][j];                                       \
      }                                                                        \
    }                                                                          \
  }

  u16x8 vreg[4];
  STAGE_K(0, 0);
  LOAD_V(0, vreg);
  WRITE_V(vreg, 0);
  __syncthreads();  // drains K gloads (vmcnt0) + V writes

  for (int t = 0; t < nt; ++t) {
    const int p = t & 1;
    const int kv0 = t * 64;
    const bool more = (t + 1 < nt);
    u16x8 vnext[4];
    if (more) {
      STAGE_K(kv0 + 64, p ^ 1);   // async into other buffer
      LOAD_V(kv0 + 64, vnext);    // into regs; consumed at bottom
    }

    // S = Q K^T  (16 q-rows x 64 kv per wave), K from swizzled LDS
    f32x4 s[4] = {};
#pragma unroll
    for (int ks = 0; ks < 4; ++ks) {
#pragma unroll
      for (int n = 0; n < 4; ++n) {
        int row16 = n * 16 + l15;
        bf16x8 kf = *(const bf16x8*)&Ksh[p][row16 * 128 +
                                            (((ks * 4 + lg) ^ (row16 & 7)) * 8)];
        s[n] = __builtin_amdgcn_mfma_f32_16x16x32_bf16(qa[ks], kf, s[n], 0, 0, 0);
      }
    }

    // online softmax
    const bool diag = (t == nt - 1);
    float alpha[4];
#pragma unroll
    for (int r = 0; r < 4; ++r) {
      int tq = q0 + w * 16 + lg * 4 + r;
      float mx = -1e30f;
#pragma unroll
      for (int n = 0; n < 4; ++n) {
        float v = s[n][r] * scale;
        if (diag && (kv0 + n * 16 + l15) > tq) v = -1e30f;
        s[n][r] = v;
        mx = fmaxf(mx, v);
      }
#pragma unroll
      for (int msk = 1; msk < 16; msk <<= 1) mx = fmaxf(mx, __shfl_xor(mx, msk, 64));
      float mn = fmaxf(m[r], mx);
      alpha[r] = __expf(m[r] - mn);
      m[r] = mn;
      float ps = 0.f;
#pragma unroll
      for (int n = 0; n < 4; ++n) {
        float pv = __expf(s[n][r] - mn);
        s[n][r] = pv;
        ps += pv;
      }
#pragma unroll
      for (int msk = 1; msk < 16; msk <<= 1) ps += __shfl_xor(ps, msk, 64);
      lsum[r] = lsum[r] * alpha[r] + ps;
      int prow = lg * 4 + r;
#pragma unroll
      for (int n = 0; n < 4; ++n)
        Psh[w][prow * 64 + (((n * 2 + (l15 >> 3)) ^ (prow & 7)) * 8) + (l15 & 7)] =
            f2bf(s[n][r]);
    }
#pragma unroll
    for (int f = 0; f < 8; ++f)
#pragma unroll
      for (int r = 0; r < 4; ++r) acc_o[f][r] *= alpha[r];

    // O += P V  (P wave-local, V^T from swizzled LDS)
#pragma unroll
    for (int ks = 0; ks < 2; ++ks) {
      bf16x8 pa = *(const bf16x8*)&Psh[w][l15 * 64 + (((ks * 4 + lg) ^ (l15 & 7)) * 8)];
#pragma unroll
      for (int nd = 0; nd < 8; ++nd) {
        int d = nd * 16 + l15;
        bf16x8 bv = *(const bf16x8*)&Vsh[p][d * 64 +
                        (((ks * 4 + lg) ^ (d & 7) ^ ((d >> 3) & 7)) * 8)];
        acc_o[nd] = __builtin_amdgcn_mfma_f32_16x16x32_bf16(pa, bv, acc_o[nd], 0, 0, 0);
      }
    }

    if (more) WRITE_V(vnext, p ^ 1);  // compiler waits vmcnt for vnext here
    __syncthreads();                   // one barrier per tile: staging t+1 done
  }

  // epilogue
#pragma unroll
  for (int nd = 0; nd < 8; ++nd)
#pragma unroll
    for (int r = 0; r < 4; ++r) {
      int row = q0 + w * 16 + lg * 4 + r;
      int col = h * HDIM + nd * 16 + l15;
      out[(size_t)row * (NHEAD * HDIM) + col] = f2bf(acc_o[nd][r] / lsum[r]);
    }
#undef STAGE_K
#undef LOAD_V
#undef WRITE_V
}

// ---------------- launcher ----------------
extern "C" void kernel_launch(void* const* d_in, const int* in_sizes, int n_in,
                              void* d_out, int out_size, void* d_ws, size_t ws_size,
                              hipStream_t stream) {
  const float* hs   = (const float*)d_in[0];
  const int*   pos  = (const int*)d_in[1];
  const float* wqkv = (const float*)d_in[2];
  const float* wo   = (const float*)d_in[3];
  float* out = (float*)d_out;
  uint8_t* ws = (uint8_t*)d_ws;

  if (ws_size < 142606336u) return;
  u16* hs_bf   = (u16*)(ws + 0);
  u16* wqkv_bf = (u16*)(ws + 16777216u);
  u16* wo_bf   = (u16*)(ws + 67108864u);
  u16* qkv_bf  = (u16*)(ws + 100663296u);
  u16* attn_bf = (u16*)(ws + 125829120u);

  cvt_f32_bf16<<<2048, 256, 0, stream>>>(hs, hs_bf, T_SEQ * HIDDEN);
  cvt_f32_bf16<<<2048, 256, 0, stream>>>(wqkv, wqkv_bf, QKVN * HIDDEN);
  cvt_f32_bf16<<<2048, 256, 0, stream>>>(wo, wo_bf, HIDDEN * HIDDEN);

  gemm_nt<u16><<<dim3(QKVN / 128, T_SEQ / 128), 256, 0, stream>>>(
      hs_bf, wqkv_bf, qkv_bf, T_SEQ, QKVN, HIDDEN);

  rope_kernel<<<(T_SEQ * 40 * 64) / 256, 256, 0, stream>>>(qkv_bf, pos);

  attn_kernel<<<1024, 256, 0, stream>>>(qkv_bf, attn_bf);

  gemm_nt<float><<<dim3(HIDDEN / 128, T_SEQ / 128), 256, 0, stream>>>(
      attn_bf, wo_bf, out, T_SEQ, HIDDEN, HIDDEN);
}